// Round 15
// baseline (139.265 us; speedup 1.0000x reference)
//
#include <hip/hip_runtime.h>
#include <math.h>

#define H 256
#define HH 128
#define B_GRAPHS 512

typedef __attribute__((ext_vector_type(8))) short bfrag8;   // 8 bf16
typedef __attribute__((ext_vector_type(16))) float f32x16;

// ---------------- K0: fused prep: W1 split (blocks 0..127) + seg bounds (blocks 128..130) ----
__global__ void k_prep(const float* __restrict__ W1, ushort* __restrict__ W1b,
                       const int* __restrict__ batch, int* __restrict__ seg_start,
                       int N, int B) {
  const int blk = blockIdx.x;
  if (blk < 128) {
    const int idx = blk * 256 + threadIdx.x;  // 32768 = 256*128
    const int k = idx >> 7, c = idx & 127;
    const float v = W1[idx];  // W1 is [256][128] row-major
    const uint u = __builtin_bit_cast(uint, v);
    const float r = v - __builtin_bit_cast(float, u & 0xFFFF0000u);
    const int base = (((k >> 4) * 2 + ((k >> 3) & 1)) * 128 + c) * 8 + (k & 7);
    W1b[base] = (ushort)(u >> 16);
    W1b[32768 + base] = (ushort)(__builtin_bit_cast(uint, r) >> 16);
  } else {
    const int b = (blk - 128) * 256 + threadIdx.x;
    if (b > B) return;
    int lo = 0, hi = N;
    while (lo < hi) {
      int mid = (lo + hi) >> 1;
      if (batch[mid] < b) lo = mid + 1; else hi = mid;
    }
    seg_start[b] = lo;
  }
}

// ---------------- K2: score MLP — DUAL-CHUNK per wave (2x within-wave MLP), B shared ----
__device__ __forceinline__ void splitbf(const float4 v0, const float4 v1,
                                        bfrag8& a0, bfrag8& a1) {
  const float vals[8] = {v0.x, v0.y, v0.z, v0.w, v1.x, v1.y, v1.z, v1.w};
#pragma unroll
  for (int e = 0; e < 8; ++e) {
    const uint u = __builtin_bit_cast(uint, vals[e]);
    a0[e] = (short)(u >> 16);
    const float r = vals[e] - __builtin_bit_cast(float, u & 0xFFFF0000u);
    a1[e] = (short)(__builtin_bit_cast(uint, r) >> 16);
  }
}

__global__ __launch_bounds__(256, 2) void k_score_mfma(
    const float* __restrict__ x, const ushort* __restrict__ W1b,
    const float* __restrict__ b1, const float* __restrict__ W2,
    const float* __restrict__ b2, float* __restrict__ s_out) {
  __shared__ float part[32 * 132];  // 16,896 B — epilogue scratch, reused per phase
  const int t = threadIdx.x;
  const int lane = t & 63;
  const int w = t >> 6;          // wave 0..3 = hidden quadrant
  const int nl = lane & 31, g = lane >> 5;
  const int node0 = blockIdx.x * 64;   // wave's chunk pair: [node0, node0+32), [node0+32, +64)

  // A streams: two independent chunk-streams per wave
  const float* gsrc0 = x + (size_t)(node0 + nl) * H + g * 8;
  const float* gsrc1 = gsrc0 + (size_t)32 * H;
  // B: wave w owns hid cols w*32..w*32+32; fragment-major W1b (L2-hot), SHARED by both chunks
  const ushort* bbase = W1b + ((size_t)g * 128 + w * 32 + nl) * 8;

  f32x16 accA0 = (f32x16)0.f, accA1 = (f32x16)0.f;  // chunk 0
  f32x16 accB0 = (f32x16)0.f, accB1 = (f32x16)0.f;  // chunk 1

  // depth-1 rolling prefetch for both x streams
  float4 xa0 = *(const float4*)(gsrc0);
  float4 xa1 = *(const float4*)(gsrc0 + 4);
  float4 ya0 = *(const float4*)(gsrc1);
  float4 ya1 = *(const float4*)(gsrc1 + 4);

#pragma unroll
  for (int kks = 0; kks < 16; ++kks) {
    float4 xn0, xn1, yn0, yn1;
    if (kks < 15) {
      xn0 = *(const float4*)(gsrc0 + (kks + 1) * 16);
      xn1 = *(const float4*)(gsrc0 + (kks + 1) * 16 + 4);
      yn0 = *(const float4*)(gsrc1 + (kks + 1) * 16);
      yn1 = *(const float4*)(gsrc1 + (kks + 1) * 16 + 4);
    }
    const bfrag8 b0 = *(const bfrag8*)(bbase + (size_t)kks * 2048);
    const bfrag8 b1f = *(const bfrag8*)(bbase + (size_t)kks * 2048 + 32768);
    bfrag8 a0, a1, c0, c1;
    splitbf(xa0, xa1, a0, a1);
    splitbf(ya0, ya1, c0, c1);
    // interleaved: two independent MFMA dependency chains
    accA0 = __builtin_amdgcn_mfma_f32_32x32x16_bf16(a0, b0, accA0, 0, 0, 0);
    accB0 = __builtin_amdgcn_mfma_f32_32x32x16_bf16(c0, b0, accB0, 0, 0, 0);
    accA1 = __builtin_amdgcn_mfma_f32_32x32x16_bf16(a0, b1f, accA1, 0, 0, 0);
    accB1 = __builtin_amdgcn_mfma_f32_32x32x16_bf16(c0, b1f, accB1, 0, 0, 0);
    accA0 = __builtin_amdgcn_mfma_f32_32x32x16_bf16(a1, b0, accA0, 0, 0, 0);
    accB0 = __builtin_amdgcn_mfma_f32_32x32x16_bf16(c1, b0, accB0, 0, 0, 0);
    if (kks < 15) {
      xa0 = xn0; xa1 = xn1; ya0 = yn0; ya1 = yn1;
    }
  }

  // ---- epilogue: two phases (chunk 0, chunk 1); R12-proven combine ----
  const float b2v = b2[0];
#pragma unroll
  for (int P = 0; P < 2; ++P) {
    if (P == 1) __syncthreads();
#pragma unroll
    for (int r = 0; r < 16; ++r) {
      const int row = (r & 3) + 8 * (r >> 2) + 4 * g;
      const float v = (P == 0) ? (accA0[r] + accA1[r]) : (accB0[r] + accB1[r]);
      part[row * 132 + w * 32 + nl] = v;
    }
    __syncthreads();
    {
      const int node = t >> 3, seg = t & 7;
      float v = 0.f;
#pragma unroll
      for (int e = 0; e < 16; ++e) {
        const int hcol = seg * 16 + e;
        const float hv = part[node * 132 + hcol] + b1[hcol];
        v = fmaf(fmaxf(hv, 0.f), W2[hcol], v);
      }
#pragma unroll
      for (int m = 1; m <= 4; m <<= 1) v += __shfl_xor(v, m);
      if ((t & 7) == 0) s_out[node0 + P * 32 + node] = v + b2v;
    }
  }
}

// ---------------- K3: fused softmax stats + top-k select + single-pass pools ----------------
__global__ __launch_bounds__(512) void k_pool_fused(const float* __restrict__ x,
                                                    const float* __restrict__ s,
                                                    const int* __restrict__ seg_start,
                                                    float* __restrict__ pooled) {
  const int b = blockIdx.x;
  const int t = threadIdx.x;
  const int start = seg_start[b];
  const int end = seg_start[b + 1];
  const int n = end - start;

  __shared__ float s_lds[1024];
  __shared__ float red[512];
  __shared__ float thr_sh;
  __shared__ int thri_sh;
  __shared__ float r4[8][264];

  const bool fits = (n <= 1024);
  if (fits) {
    for (int i = t; i < n; i += 512) s_lds[i] = s[start + i];
  }
  __syncthreads();
  const float* sseg = fits ? s_lds : (s + start);

  float m = -INFINITY;
  for (int i = t; i < n; i += 512) m = fmaxf(m, sseg[i]);
  red[t] = m;
  __syncthreads();
  for (int off = 256; off > 0; off >>= 1) {
    if (t < off) red[t] = fmaxf(red[t], red[t + off]);
    __syncthreads();
  }
  const float smax = red[0];
  __syncthreads();
  float d = 0.f;
  for (int i = t; i < n; i += 512) d += __expf(sseg[i] - smax);
  red[t] = d;
  __syncthreads();
  for (int off = 256; off > 0; off >>= 1) {
    if (t < off) red[t] += red[t + off];
    __syncthreads();
  }
  const float denom = red[0];
  __syncthreads();
  const float inv_denom = (denom > 0.f) ? 1.f / denom : 0.f;

  int k = 0;
  if (n > 0) {
    k = (int)ceilf(0.05f * (float)n);
    if (k < 5) k = 5;
    if (k > 64) k = 64;
    if (k > n) k = n;
  }

  if (t < 64) {
    float pk = INFINITY;
    int pidx = -1;
    for (int r = 0; r < k; ++r) {
      float bk = -INFINITY;
      int bi = 0x7fffffff;
      for (int i = t; i < n; i += 64) {
        const float si = sseg[i];
        const int gi = start + i;
        const bool below = (si < pk) || (si == pk && gi > pidx);
        if (below && (si > bk || (si == bk && gi < bi))) { bk = si; bi = gi; }
      }
#pragma unroll
      for (int off = 32; off > 0; off >>= 1) {
        const float ok = __shfl_xor(bk, off);
        const int oi = __shfl_xor(bi, off);
        if (ok > bk || (ok == bk && oi < bi)) { bk = ok; bi = oi; }
      }
      pk = bk;
      pidx = bi;
    }
    if (t == 0) {
      thr_sh = (k > 0) ? pk : INFINITY;
      thri_sh = (k > 0) ? pidx : -1;
    }
  }
  __syncthreads();
  const float thr = thr_sh;
  const int thri = thri_sh;

  const int fq = t & 63;
  const int sub = t >> 6;
  float mean[4] = {0.f, 0.f, 0.f, 0.f};
  float attn[4] = {0.f, 0.f, 0.f, 0.f};
  float tk[4] = {0.f, 0.f, 0.f, 0.f};
  float mx[4] = {-INFINITY, -INFINITY, -INFINITY, -INFINITY};
  for (int i = sub; i < n; i += 8) {
    const float si = sseg[i];
    const float wi = __expf(si - smax);
    const int gi = start + i;
    const bool sel = (si > thr) || (si == thr && gi <= thri);
    const float4 xv = *reinterpret_cast<const float4*>(x + (size_t)gi * H + fq * 4);
    mean[0] += xv.x; mean[1] += xv.y; mean[2] += xv.z; mean[3] += xv.w;
    attn[0] = fmaf(xv.x, wi, attn[0]);
    attn[1] = fmaf(xv.y, wi, attn[1]);
    attn[2] = fmaf(xv.z, wi, attn[2]);
    attn[3] = fmaf(xv.w, wi, attn[3]);
    mx[0] = fmaxf(mx[0], xv.x);
    mx[1] = fmaxf(mx[1], xv.y);
    mx[2] = fmaxf(mx[2], xv.z);
    mx[3] = fmaxf(mx[3], xv.w);
    if (sel) {
      tk[0] += xv.x; tk[1] += xv.y; tk[2] += xv.z; tk[3] += xv.w;
    }
  }
  float* po = pooled + (size_t)b * 1024;
  const float invn = 1.f / (float)(n > 0 ? n : 1);
  const float invk = (k > 0) ? 1.f / (float)k : 0.f;
  *reinterpret_cast<float4*>(&r4[sub][fq * 4]) = make_float4(mean[0], mean[1], mean[2], mean[3]);
  __syncthreads();
  if (t < 256) {
    float tot = 0.f;
#pragma unroll
    for (int q = 0; q < 8; ++q) tot += r4[q][t];
    po[t] = tot * invn;
  }
  __syncthreads();
  *reinterpret_cast<float4*>(&r4[sub][fq * 4]) = make_float4(attn[0], attn[1], attn[2], attn[3]);
  __syncthreads();
  if (t < 256) {
    float tot = 0.f;
#pragma unroll
    for (int q = 0; q < 8; ++q) tot += r4[q][t];
    po[256 + t] = tot * inv_denom;
  }
  __syncthreads();
  *reinterpret_cast<float4*>(&r4[sub][fq * 4]) = make_float4(mx[0], mx[1], mx[2], mx[3]);
  __syncthreads();
  if (t < 256) {
    float tot = -INFINITY;
#pragma unroll
    for (int q = 0; q < 8; ++q) tot = fmaxf(tot, r4[q][t]);
    po[512 + t] = (n > 0) ? tot : 0.f;
  }
  __syncthreads();
  *reinterpret_cast<float4*>(&r4[sub][fq * 4]) = make_float4(tk[0], tk[1], tk[2], tk[3]);
  __syncthreads();
  if (t < 256) {
    float tot = 0.f;
#pragma unroll
    for (int q = 0; q < 8; ++q) tot += r4[q][t];
    po[768 + t] = tot * invk;
  }
}

// ---------------- K5: final GEMM [512,1024]@[1024,256], split-K=8 (R10 verbatim) --------
__global__ __launch_bounds__(256) void k_gemm(const float* __restrict__ pooled,
                                              const float* __restrict__ Wf,
                                              float* __restrict__ gacc) {
  const int t = threadIdx.x;
  const int r0 = blockIdx.x * 8;
  const int kc0 = blockIdx.y * 128;
  __shared__ float ps[8][132];
  {
    const int r = t >> 5;
    const int c = (t & 31) << 2;
    *reinterpret_cast<float4*>(&ps[r][c]) =
        *reinterpret_cast<const float4*>(pooled + (size_t)(r0 + r) * 1024 + kc0 + c);
  }
  __syncthreads();
  float acc[8];
#pragma unroll
  for (int r = 0; r < 8; ++r) acc[r] = 0.f;
#pragma unroll 4
  for (int c = 0; c < 128; ++c) {
    const float wf = Wf[(size_t)(kc0 + c) * 256 + t];
#pragma unroll
    for (int r = 0; r < 8; ++r) acc[r] = fmaf(ps[r][c], wf, acc[r]);
  }
  float* go = gacc + ((size_t)blockIdx.y * B_GRAPHS + r0) * 256;
#pragma unroll
  for (int r = 0; r < 8; ++r) go[r * 256 + t] = acc[r];
}

// ---------------- K6: reduce split-K + bias + relu -> out (R10 verbatim) ----------------
__global__ __launch_bounds__(256) void k_out(const float* __restrict__ gacc,
                                             const float* __restrict__ bf,
                                             float* __restrict__ out) {
  const int i = blockIdx.x * 256 + threadIdx.x;
  float v = bf[i & 255];
#pragma unroll
  for (int ks = 0; ks < 8; ++ks) v += gacc[(size_t)ks * (B_GRAPHS * 256) + i];
  out[i] = fmaxf(v, 0.f);
}

extern "C" void kernel_launch(void* const* d_in, const int* in_sizes, int n_in,
                              void* d_out, int out_size, void* d_ws, size_t ws_size,
                              hipStream_t stream) {
  const float* x  = (const float*)d_in[0];
  const int* batch = (const int*)d_in[1];
  const float* W1 = (const float*)d_in[2];
  const float* b1 = (const float*)d_in[3];
  const float* W2 = (const float*)d_in[4];
  const float* b2 = (const float*)d_in[5];
  const float* Wf = (const float*)d_in[6];
  const float* bf = (const float*)d_in[7];
  const int N = in_sizes[1];     // 131072
  const int B = B_GRAPHS;

  // ws floats: s[N] | seg_start[1024 ints] | pooled[B*1024] | gacc[8*B*256] | W1b[2*32768 u16]
  float* ws = (float*)d_ws;
  float* s = ws;
  int* seg_start = (int*)(ws + N);
  float* pooled = ws + N + 1024;
  float* gacc = pooled + (size_t)B * 1024;
  ushort* W1b = (ushort*)(gacc + (size_t)8 * B * 256);

  k_prep<<<dim3(131), dim3(256), 0, stream>>>(W1, W1b, batch, seg_start, N, B);
  k_score_mfma<<<dim3(N / 64), dim3(256), 0, stream>>>(x, W1b, b1, W2, b2, s);
  k_pool_fused<<<dim3(B), dim3(512), 0, stream>>>(x, s, seg_start, pooled);
  k_gemm<<<dim3(B / 8, 8), dim3(256), 0, stream>>>(pooled, Wf, gacc);
  k_out<<<dim3((B * 256) / 256), dim3(256), 0, stream>>>(gacc, bf, (float*)d_out);
}

// Round 16
// 102.763 us; speedup vs baseline: 1.3552x; 1.3552x over previous
//
#include <hip/hip_runtime.h>
#include <math.h>

#define H 256
#define HH 128
#define B_GRAPHS 512

typedef __attribute__((ext_vector_type(8))) short bfrag8;   // 8 bf16
typedef __attribute__((ext_vector_type(16))) float f32x16;

// ---------------- K0: fused prep: W1 split (blocks 0..127) + seg bounds (blocks 128..130) ----
__global__ void k_prep(const float* __restrict__ W1, ushort* __restrict__ W1b,
                       const int* __restrict__ batch, int* __restrict__ seg_start,
                       int N, int B) {
  const int blk = blockIdx.x;
  if (blk < 128) {
    const int idx = blk * 256 + threadIdx.x;  // 32768 = 256*128
    const int k = idx >> 7, c = idx & 127;
    const float v = W1[idx];  // W1 is [256][128] row-major
    const uint u = __builtin_bit_cast(uint, v);
    const float r = v - __builtin_bit_cast(float, u & 0xFFFF0000u);
    const int base = (((k >> 4) * 2 + ((k >> 3) & 1)) * 128 + c) * 8 + (k & 7);
    W1b[base] = (ushort)(u >> 16);
    W1b[32768 + base] = (ushort)(__builtin_bit_cast(uint, r) >> 16);
  } else {
    const int b = (blk - 128) * 256 + threadIdx.x;
    if (b > B) return;
    int lo = 0, hi = N;
    while (lo < hi) {
      int mid = (lo + hi) >> 1;
      if (batch[mid] < b) lo = mid + 1; else hi = mid;
    }
    seg_start[b] = lo;
  }
}

// ---------------- K2: score MLP — whole W1 resident in LDS, barrier-free main loop ------
// (R10/R14-measured-best configuration, verbatim)
__device__ __forceinline__ void splitbf(const float4 v0, const float4 v1,
                                        bfrag8& a0, bfrag8& a1) {
  const float vals[8] = {v0.x, v0.y, v0.z, v0.w, v1.x, v1.y, v1.z, v1.w};
#pragma unroll
  for (int e = 0; e < 8; ++e) {
    const uint u = __builtin_bit_cast(uint, vals[e]);
    a0[e] = (short)(u >> 16);
    const float r = vals[e] - __builtin_bit_cast(float, u & 0xFFFF0000u);
    a1[e] = (short)(__builtin_bit_cast(uint, r) >> 16);
  }
}

__global__ __launch_bounds__(1024, 4) void k_score_mfma(
    const float* __restrict__ x, const ushort* __restrict__ W1b,
    const float* __restrict__ b1, const float* __restrict__ W2,
    const float* __restrict__ b2, float* __restrict__ s_out) {
  extern __shared__ ushort bsh[];  // 131072 B: plane0 [32768], plane1 [32768]
  const int t = threadIdx.x;
  const int lane = t & 63;
  const int w = t >> 6;          // 0..15
  const int nl = lane & 31, g = lane >> 5;

  // ---- stage full W1b into LDS (once), coalesced: 128 B per thread ----
  {
    const uint4* src = (const uint4*)W1b + t * 8;
    uint4* dst = (uint4*)bsh + t * 8;
#pragma unroll
    for (int i = 0; i < 8; ++i) dst[i] = src[i];
  }
  __syncthreads();

  const int chunk = blockIdx.x * 16 + w;   // 256 blocks * 16 waves = 4096 chunks
  const int node0 = chunk * 32;
  const float* gsrc = x + (size_t)(node0 + nl) * H + g * 8;

  f32x16 acc[4];
  acc[0] = (f32x16)0.f; acc[1] = (f32x16)0.f;
  acc[2] = (f32x16)0.f; acc[3] = (f32x16)0.f;

  // rolling 2-substep batches of A loads (32 B/lane/substep, full-line coalesced)
  float4 xa[2][2], xb[2][2];
#pragma unroll
  for (int q = 0; q < 2; ++q) {
    xa[q][0] = *(const float4*)(gsrc + q * 16);
    xa[q][1] = *(const float4*)(gsrc + q * 16 + 4);
  }

#pragma unroll
  for (int pair = 0; pair < 8; ++pair) {
    if (pair < 7) {
#pragma unroll
      for (int q = 0; q < 2; ++q) {
        xb[q][0] = *(const float4*)(gsrc + ((pair + 1) * 2 + q) * 16);
        xb[q][1] = *(const float4*)(gsrc + ((pair + 1) * 2 + q) * 16 + 4);
      }
    }
#pragma unroll
    for (int q = 0; q < 2; ++q) {
      const int kks = pair * 2 + q;
      bfrag8 a0, a1;
      splitbf(xa[q][0], xa[q][1], a0, a1);
#pragma unroll
      for (int j = 0; j < 4; ++j) {
        const ushort* bp = &bsh[(size_t)((kks * 2 + g) * 128 + j * 32 + nl) * 8];
        const bfrag8 b0 = *(const bfrag8*)bp;
        const bfrag8 b1f = *(const bfrag8*)(bp + 32768);
        acc[j] = __builtin_amdgcn_mfma_f32_32x32x16_bf16(a0, b0, acc[j], 0, 0, 0);
        acc[j] = __builtin_amdgcn_mfma_f32_32x32x16_bf16(a0, b1f, acc[j], 0, 0, 0);
        acc[j] = __builtin_amdgcn_mfma_f32_32x32x16_bf16(a1, b0, acc[j], 0, 0, 0);
      }
    }
    if (pair < 7) {
#pragma unroll
      for (int q = 0; q < 2; ++q) {
        xa[q][0] = xb[q][0];
        xa[q][1] = xb[q][1];
      }
    }
  }

  // ---- epilogue: layer 2 + cross-lane reduce (proven C/D map: row=(r&3)+8*(r>>2)+4g) ----
  float b1v[4], w2v[4];
#pragma unroll
  for (int j = 0; j < 4; ++j) {
    b1v[j] = b1[j * 32 + nl];
    w2v[j] = W2[j * 32 + nl];
  }
  float p[16];
#pragma unroll
  for (int r = 0; r < 16; ++r) {
    float v = 0.f;
#pragma unroll
    for (int j = 0; j < 4; ++j)
      v = fmaf(fmaxf(acc[j][r] + b1v[j], 0.f), w2v[j], v);
#pragma unroll
    for (int m = 1; m <= 16; m <<= 1) v += __shfl_xor(v, m);
    p[r] = v;
  }
  if (nl == 0) {
    const float bb = b2[0];
#pragma unroll
    for (int r = 0; r < 16; ++r) {
      const int row = (r & 3) + 8 * (r >> 2) + 4 * g;
      s_out[node0 + row] = p[r] + bb;
    }
  }
}

// ---------------- K3: fused softmax stats + top-k select + single-pass pools ----------------
__global__ __launch_bounds__(512) void k_pool_fused(const float* __restrict__ x,
                                                    const float* __restrict__ s,
                                                    const int* __restrict__ seg_start,
                                                    float* __restrict__ pooled) {
  const int b = blockIdx.x;
  const int t = threadIdx.x;
  const int start = seg_start[b];
  const int end = seg_start[b + 1];
  const int n = end - start;

  __shared__ float s_lds[1024];
  __shared__ float red[512];
  __shared__ float thr_sh;
  __shared__ int thri_sh;
  __shared__ float r4[8][264];

  const bool fits = (n <= 1024);
  if (fits) {
    for (int i = t; i < n; i += 512) s_lds[i] = s[start + i];
  }
  __syncthreads();
  const float* sseg = fits ? s_lds : (s + start);

  float m = -INFINITY;
  for (int i = t; i < n; i += 512) m = fmaxf(m, sseg[i]);
  red[t] = m;
  __syncthreads();
  for (int off = 256; off > 0; off >>= 1) {
    if (t < off) red[t] = fmaxf(red[t], red[t + off]);
    __syncthreads();
  }
  const float smax = red[0];
  __syncthreads();
  float d = 0.f;
  for (int i = t; i < n; i += 512) d += __expf(sseg[i] - smax);
  red[t] = d;
  __syncthreads();
  for (int off = 256; off > 0; off >>= 1) {
    if (t < off) red[t] += red[t + off];
    __syncthreads();
  }
  const float denom = red[0];
  __syncthreads();
  const float inv_denom = (denom > 0.f) ? 1.f / denom : 0.f;

  int k = 0;
  if (n > 0) {
    k = (int)ceilf(0.05f * (float)n);
    if (k < 5) k = 5;
    if (k > 64) k = 64;
    if (k > n) k = n;
  }

  if (t < 64) {
    float pk = INFINITY;
    int pidx = -1;
    for (int r = 0; r < k; ++r) {
      float bk = -INFINITY;
      int bi = 0x7fffffff;
      for (int i = t; i < n; i += 64) {
        const float si = sseg[i];
        const int gi = start + i;
        const bool below = (si < pk) || (si == pk && gi > pidx);
        if (below && (si > bk || (si == bk && gi < bi))) { bk = si; bi = gi; }
      }
#pragma unroll
      for (int off = 32; off > 0; off >>= 1) {
        const float ok = __shfl_xor(bk, off);
        const int oi = __shfl_xor(bi, off);
        if (ok > bk || (ok == bk && oi < bi)) { bk = ok; bi = oi; }
      }
      pk = bk;
      pidx = bi;
    }
    if (t == 0) {
      thr_sh = (k > 0) ? pk : INFINITY;
      thri_sh = (k > 0) ? pidx : -1;
    }
  }
  __syncthreads();
  const float thr = thr_sh;
  const int thri = thri_sh;

  const int fq = t & 63;
  const int sub = t >> 6;
  float mean[4] = {0.f, 0.f, 0.f, 0.f};
  float attn[4] = {0.f, 0.f, 0.f, 0.f};
  float tk[4] = {0.f, 0.f, 0.f, 0.f};
  float mx[4] = {-INFINITY, -INFINITY, -INFINITY, -INFINITY};
  for (int i = sub; i < n; i += 8) {
    const float si = sseg[i];
    const float wi = __expf(si - smax);
    const int gi = start + i;
    const bool sel = (si > thr) || (si == thr && gi <= thri);
    const float4 xv = *reinterpret_cast<const float4*>(x + (size_t)gi * H + fq * 4);
    mean[0] += xv.x; mean[1] += xv.y; mean[2] += xv.z; mean[3] += xv.w;
    attn[0] = fmaf(xv.x, wi, attn[0]);
    attn[1] = fmaf(xv.y, wi, attn[1]);
    attn[2] = fmaf(xv.z, wi, attn[2]);
    attn[3] = fmaf(xv.w, wi, attn[3]);
    mx[0] = fmaxf(mx[0], xv.x);
    mx[1] = fmaxf(mx[1], xv.y);
    mx[2] = fmaxf(mx[2], xv.z);
    mx[3] = fmaxf(mx[3], xv.w);
    if (sel) {
      tk[0] += xv.x; tk[1] += xv.y; tk[2] += xv.z; tk[3] += xv.w;
    }
  }
  float* po = pooled + (size_t)b * 1024;
  const float invn = 1.f / (float)(n > 0 ? n : 1);
  const float invk = (k > 0) ? 1.f / (float)k : 0.f;
  *reinterpret_cast<float4*>(&r4[sub][fq * 4]) = make_float4(mean[0], mean[1], mean[2], mean[3]);
  __syncthreads();
  if (t < 256) {
    float tot = 0.f;
#pragma unroll
    for (int q = 0; q < 8; ++q) tot += r4[q][t];
    po[t] = tot * invn;
  }
  __syncthreads();
  *reinterpret_cast<float4*>(&r4[sub][fq * 4]) = make_float4(attn[0], attn[1], attn[2], attn[3]);
  __syncthreads();
  if (t < 256) {
    float tot = 0.f;
#pragma unroll
    for (int q = 0; q < 8; ++q) tot += r4[q][t];
    po[256 + t] = tot * inv_denom;
  }
  __syncthreads();
  *reinterpret_cast<float4*>(&r4[sub][fq * 4]) = make_float4(mx[0], mx[1], mx[2], mx[3]);
  __syncthreads();
  if (t < 256) {
    float tot = -INFINITY;
#pragma unroll
    for (int q = 0; q < 8; ++q) tot = fmaxf(tot, r4[q][t]);
    po[512 + t] = (n > 0) ? tot : 0.f;
  }
  __syncthreads();
  *reinterpret_cast<float4*>(&r4[sub][fq * 4]) = make_float4(tk[0], tk[1], tk[2], tk[3]);
  __syncthreads();
  if (t < 256) {
    float tot = 0.f;
#pragma unroll
    for (int q = 0; q < 8; ++q) tot += r4[q][t];
    po[768 + t] = tot * invk;
  }
}

// ---------------- K5: final GEMM [512,1024]@[1024,256], split-K=8 (R10 verbatim) --------
__global__ __launch_bounds__(256) void k_gemm(const float* __restrict__ pooled,
                                              const float* __restrict__ Wf,
                                              float* __restrict__ gacc) {
  const int t = threadIdx.x;
  const int r0 = blockIdx.x * 8;
  const int kc0 = blockIdx.y * 128;
  __shared__ float ps[8][132];
  {
    const int r = t >> 5;
    const int c = (t & 31) << 2;
    *reinterpret_cast<float4*>(&ps[r][c]) =
        *reinterpret_cast<const float4*>(pooled + (size_t)(r0 + r) * 1024 + kc0 + c);
  }
  __syncthreads();
  float acc[8];
#pragma unroll
  for (int r = 0; r < 8; ++r) acc[r] = 0.f;
#pragma unroll 4
  for (int c = 0; c < 128; ++c) {
    const float wf = Wf[(size_t)(kc0 + c) * 256 + t];
#pragma unroll
    for (int r = 0; r < 8; ++r) acc[r] = fmaf(ps[r][c], wf, acc[r]);
  }
  float* go = gacc + ((size_t)blockIdx.y * B_GRAPHS + r0) * 256;
#pragma unroll
  for (int r = 0; r < 8; ++r) go[r * 256 + t] = acc[r];
}

// ---------------- K6: reduce split-K + bias + relu -> out (R10 verbatim) ----------------
__global__ __launch_bounds__(256) void k_out(const float* __restrict__ gacc,
                                             const float* __restrict__ bf,
                                             float* __restrict__ out) {
  const int i = blockIdx.x * 256 + threadIdx.x;
  float v = bf[i & 255];
#pragma unroll
  for (int ks = 0; ks < 8; ++ks) v += gacc[(size_t)ks * (B_GRAPHS * 256) + i];
  out[i] = fmaxf(v, 0.f);
}

extern "C" void kernel_launch(void* const* d_in, const int* in_sizes, int n_in,
                              void* d_out, int out_size, void* d_ws, size_t ws_size,
                              hipStream_t stream) {
  const float* x  = (const float*)d_in[0];
  const int* batch = (const int*)d_in[1];
  const float* W1 = (const float*)d_in[2];
  const float* b1 = (const float*)d_in[3];
  const float* W2 = (const float*)d_in[4];
  const float* b2 = (const float*)d_in[5];
  const float* Wf = (const float*)d_in[6];
  const float* bf = (const float*)d_in[7];
  const int N = in_sizes[1];     // 131072
  const int B = B_GRAPHS;

  // ws floats: s[N] | seg_start[1024 ints] | pooled[B*1024] | gacc[8*B*256] | W1b[2*32768 u16]
  float* ws = (float*)d_ws;
  float* s = ws;
  int* seg_start = (int*)(ws + N);
  float* pooled = ws + N + 1024;
  float* gacc = pooled + (size_t)B * 1024;
  ushort* W1b = (ushort*)(gacc + (size_t)8 * B * 256);

  static bool attr_set = false;
  if (!attr_set) {
    hipFuncSetAttribute((const void*)k_score_mfma,
                        hipFuncAttributeMaxDynamicSharedMemorySize, 131072);
    attr_set = true;
  }

  k_prep<<<dim3(131), dim3(256), 0, stream>>>(W1, W1b, batch, seg_start, N, B);
  k_score_mfma<<<dim3(N / 512), dim3(1024), 131072, stream>>>(x, W1b, b1, W2, b2, s);
  k_pool_fused<<<dim3(B), dim3(512), 0, stream>>>(x, s, seg_start, pooled);
  k_gemm<<<dim3(B / 8, 8), dim3(256), 0, stream>>>(pooled, Wf, gacc);
  k_out<<<dim3((B * 256) / 256), dim3(256), 0, stream>>>(gacc, bf, (float*)d_out);
}